// Round 12
// baseline (463.541 us; speedup 1.0000x reference)
//
#include <hip/hip_runtime.h>
#include <math.h>

// Problem constants
#define GG 16
#define NNODE 512
#define EEDGE 2048
#define KEEPN 256
#define PITERS 64
#define NNT 8192    // G*N
#define NET 32768   // G*E

typedef float vfloat4 __attribute__((ext_vector_type(4)));

// workspace float offsets
#define WS_C1N 0        // c1 node (mp1 input; dead after mp1)
#define WS_C2N 8192
#define WS_BN  16384
#define WS_C1E 24576
#define WS_C2E 57344
#define WS_BE  90112
#define WS_SNW 122880   // masked node score (written by k_pool)
#define WS_SEW 131072   // masked edge score (written by k_pool)
#define WS_KLIST 163840 // int[32768]
#define WS_KCNT 196608  // int[16]
#define WS_SCALE 196624 // float[16]

// output float offsets: xn | L0 | xe | L1
#define O_XN 0
#define O_L0 524288
#define O_XE 4718592
#define O_L1 6815744

// MP accumulators in the L0 region of out (zeroed by k_dots riders, READ by
// k_pool workers; all zero riders SKIP this region; k_out g=0 block zeroes it).
#define AC_D1N 0        // 8192
#define AC_D2N 8192     // 8192
#define AC_E2N 16384    // 8192
#define AC_D1E 24576    // 32768
#define AC_D2E 57344    // 32768
#define AC_E2E 90112    // 32768
#define AC_TOT4 30720   // 122880 floats / 4 (first 30720 f4 of L0)

// zero-space: float4 indices over concatenated L0 (1,048,576 f4) || L1
#define L04 1048576
#define ZTOT4 17825792   // 272 MiB
// zero partition (f4): [AC_TOT4, +3932160) mp1 | [+3932160, +7864320) mp2 |
// [AC_TOT4+7864320, ZTOT4) pool
#define Z_MP1_LO (AC_TOT4)
#define Z_MP2_LO (AC_TOT4 + 3932160)
#define Z_POOL_LO (AC_TOT4 + 7864320)

#define DCAP 12

// ---------------------------------------------------------------------------
// K1: channel dots (1024 blocks) + zero MP accumulator scratch (15 blocks).
__global__ __launch_bounds__(512) void k_dots(
    const float* __restrict__ xn, const float* __restrict__ xe,
    const float* __restrict__ Wn, const float* __restrict__ We,
    float* __restrict__ ws, float* __restrict__ out) {
  const int tid = threadIdx.x, bid = blockIdx.x;
  if (bid >= 1024) {
    vfloat4 z = (vfloat4)(0.f);
    vfloat4* a4 = (vfloat4*)(out + O_L0);
    int base = (bid - 1024) * 512 + tid;        // 15*512 = 7680 threads
    #pragma unroll
    for (int k = 0; k < 4; ++k) a4[base + k * 7680] = z;  // 30720 f4 exact
    return;
  }
  const int lane = tid & 63;
  const int wv = (bid * 512 + tid) >> 6;   // 0..8191
  #pragma unroll
  for (int n = 0; n < 5; ++n) {
    int gw = wv + n * 8192;                // 0..40959
    const float* x; const float* W; int row; float *c1, *c2, *bs;
    if (gw < NNT) {
      row = gw; x = xn + (size_t)row * 64; W = Wn;
      c1 = ws + WS_C1N; c2 = ws + WS_C2N; bs = ws + WS_BN;
    } else {
      row = gw - NNT;
      x = xe + (size_t)row * 64; W = We;
      c1 = ws + WS_C1E; c2 = ws + WS_C2E; bs = ws + WS_BE;
    }
    float v = x[lane];
    float r0 = v * W[lane];
    float r1 = v * W[64 + lane];
    float r2 = v * W[128 + lane];
    for (int o = 32; o; o >>= 1) {
      r0 += __shfl_xor(r0, o, 64);
      r1 += __shfl_xor(r1, o, 64);
      r2 += __shfl_xor(r2, o, 64);
    }
    if (lane == 0) { c1[row] = r1; c2[row] = r2; bs[row] = r0 + r1 + r2; }
  }
}

// ---------------------------------------------------------------------------
// K2: MP hop 1 (blocks 0..383, global atomics) + zero riders (384..1023, 60 MB).
__global__ __launch_bounds__(512) void k_mp1(
    const int* __restrict__ src_n, const int* __restrict__ dst_n, const float* __restrict__ wn,
    const int* __restrict__ src_e, const int* __restrict__ dst_e, const float* __restrict__ we,
    const float* __restrict__ ws, float* __restrict__ out) {
  const int tid = threadIdx.x, bid = blockIdx.x;
  if (bid >= 384) {
    vfloat4 z = (vfloat4)(0.f);
    vfloat4* o4 = (vfloat4*)out;
    int base = Z_MP1_LO + (bid - 384) * 512 + tid;   // 640 blocks
    #pragma unroll
    for (int n = 0; n < 12; ++n) {      // 640*512*12 = 3,932,160 exact
      int i = base + n * 327680;
      int f = (i < L04) ? (O_L0 / 4 + i) : (O_L1 / 4 + (i - L04));
      __builtin_nontemporal_store(z, &o4[f]);
    }
    return;
  }
  int gid = bid * 512 + tid;                   // [0, 196608)
  float* acc = (float*)(out + O_L0);
  if (gid < 65536) {
    int s = src_n[gid], d = dst_n[gid]; float w = wn[gid];
    atomicAdd(&acc[AC_D1N + d], w * ws[WS_C1N + s]);
    atomicAdd(&acc[AC_D2N + d], w * ws[WS_C2N + s]);
  } else {
    int e = gid - 65536;                        // [0, 131072)
    int s = src_e[e], d = dst_e[e]; float w = we[e];
    atomicAdd(&acc[AC_D1E + d], w * ws[WS_C1E + s]);
    atomicAdd(&acc[AC_D2E + d], w * ws[WS_C2E + s]);
  }
}

// ---------------------------------------------------------------------------
// K3: MP hop 2 (blocks 0..383) + zero riders (384..1023, 60 MB).
__global__ __launch_bounds__(512) void k_mp2(
    const int* __restrict__ src_n, const int* __restrict__ dst_n, const float* __restrict__ wn,
    const int* __restrict__ src_e, const int* __restrict__ dst_e, const float* __restrict__ we,
    float* __restrict__ out) {
  const int tid = threadIdx.x, bid = blockIdx.x;
  if (bid >= 384) {
    vfloat4 z = (vfloat4)(0.f);
    vfloat4* o4 = (vfloat4*)out;
    int base = Z_MP2_LO + (bid - 384) * 512 + tid;   // 640 blocks
    #pragma unroll
    for (int n = 0; n < 12; ++n) {      // next 3,932,160 exact
      int i = base + n * 327680;
      int f = (i < L04) ? (O_L0 / 4 + i) : (O_L1 / 4 + (i - L04));
      __builtin_nontemporal_store(z, &o4[f]);
    }
    return;
  }
  int gid = bid * 512 + tid;                   // [0, 196608)
  float* acc = (float*)(out + O_L0);
  if (gid < 65536) {
    int s = src_n[gid], d = dst_n[gid]; float w = wn[gid];
    atomicAdd(&acc[AC_E2N + d], w * acc[AC_D2N + s]);
  } else {
    int e = gid - 65536;
    int s = src_e[e], d = dst_e[e]; float w = we[e];
    atomicAdd(&acc[AC_E2E + d], w * acc[AC_D2E + s]);
  }
}

// ---------------------------------------------------------------------------
// K4: pool. Workers (blocks 0..15): scores + aug + rank + compact + CSR, then
// WAVE-0-ONLY barrier-free power iteration (8 nodes/lane, register-cached
// neighbor lists, zero __syncthreads in the loop). Riders: 151.5 MB zero.
#define PM_AUG  0       // 512 f
#define PM_RED  512     // 8 f (unused in power now; kept for layout)
#define PM_IWS  520     // 8 int
#define PM_KCP  528     // 1 int
#define PM_MASK 544     // 512 int
#define PM_DEG  1056    // 512 int
#define PM_OFF  1568    // 512 int
#define PM_SUV  2080    // 2048 int
#define PM_ADJ  4128    // 2048 f (4096 ushorts)
#define PM_WVA  6176    // 513 f
#define PM_WVB  6692    // 513 f
#define PM_TOT  7208

// wave-0 power step: 8 nodes/lane, no barriers; normalize every 8th iter.
#define PSTEP(WCUR, WNEXT, IT)                                             \
  {                                                                        \
    float accv[8];                                                         \
    _Pragma("unroll")                                                      \
    for (int j = 0; j < 8; ++j) {                                          \
      int n = lane + 64 * j;                                               \
      float a = (float)deg8[j] * WCUR[n];                                  \
      _Pragma("unroll")                                                    \
      for (int k = 0; k < DCAP; ++k) a -= WCUR[nbf[j * DCAP + k]];         \
      if (ovf8 & (1 << j))                                                 \
        for (int p = st8[j] + DCAP; p < st8[j] + deg8[j]; ++p)             \
          a -= WCUR[(int)adjU[p]];                                         \
      accv[j] = a;                                                         \
    }                                                                      \
    if (((IT) & 7) == 7) {                                                 \
      float sq = 0.f;                                                      \
      _Pragma("unroll")                                                    \
      for (int j = 0; j < 8; ++j) sq += accv[j] * accv[j];                 \
      for (int o = 32; o; o >>= 1) sq += __shfl_xor(sq, o, 64);            \
      float inv = 1.0f / (sqrtf(sq) + 1e-12f);                             \
      _Pragma("unroll")                                                    \
      for (int j = 0; j < 8; ++j) WNEXT[lane + 64 * j] = accv[j] * inv;    \
    } else {                                                               \
      _Pragma("unroll")                                                    \
      for (int j = 0; j < 8; ++j) WNEXT[lane + 64 * j] = accv[j];          \
    }                                                                      \
  }

__global__ __launch_bounds__(512, 2) void k_pool(
    const int* __restrict__ edge_u, const int* __restrict__ edge_v,
    const float* __restrict__ bnp, const float* __restrict__ bep,
    float* __restrict__ ws, float* __restrict__ out) {
  const int tid = threadIdx.x;
  if (blockIdx.x >= 16) {
    vfloat4 z = (vfloat4)(0.f);
    vfloat4* o4 = (vfloat4*)out;
    int base = Z_POOL_LO + (blockIdx.x - 16) * 512 + tid;
    #pragma unroll
    for (int n = 0; n < 10; ++n) {     // covers [Z_POOL_LO, ZTOT4)
      int i = base + n * 1048576;
      if (i < ZTOT4) {
        int f = (i < L04) ? (O_L0 / 4 + i) : (O_L1 / 4 + (i - L04));
        __builtin_nontemporal_store(z, &o4[f]);
      }
    }
    return;
  }
  __shared__ float smem[PM_TOT];
  int* smi = (int*)smem;
  float* aug = smem + PM_AUG;
  int* iws   = smi + PM_IWS;
  int* kcp   = smi + PM_KCP;
  int* maskS = smi + PM_MASK;
  int* degS  = smi + PM_DEG;
  int* offS  = smi + PM_OFF;
  int* suv   = smi + PM_SUV;
  unsigned short* adjU = (unsigned short*)(smi + PM_ADJ);
  float* wvA = smem + PM_WVA;
  float* wvB = smem + PM_WVB;

  const int g = blockIdx.x;
  const int roffN = g * NNODE;
  const int roffE = g * EEDGE;
  const int lane = tid & 63, wid = tid >> 6;
  const float* acc = (const float*)(out + O_L0);
  float biasN = bnp[0], biasE = bep[0];

  // ---- batched global loads for score phase ----
  float bn  = ws[WS_BN + roffN + tid];
  float nd1 = acc[AC_D1N + roffN + tid];
  float nd2 = acc[AC_D2N + roffN + tid];
  float ne2 = acc[AC_E2N + roffN + tid];
  float beR[4], d1R[4], d2R[4], e2R[4]; int uR[4], vR[4];
  #pragma unroll
  for (int n = 0; n < 4; ++n) {
    int e = roffE + tid + n * 512;
    beR[n] = ws[WS_BE + e];
    d1R[n] = acc[AC_D1E + e];
    d2R[n] = acc[AC_D2E + e];
    e2R[n] = acc[AC_E2E + e];
    uR[n] = edge_u[e];
    vR[n] = edge_v[e];
  }

  // ---- node score -> aug init ----
  float tn = bn - nd1 - 2.0f * nd2 + 0.5f * ne2 + biasN;
  float snw_r = 1.0f / (1.0f + expf(-tn));
  aug[tid] = snw_r;
  degS[tid] = 0;
  if (tid == 0) *kcp = 0;
  __syncthreads();

  // ---- edge scores -> aug atomics (LDS) ----
  float seR[4];
  #pragma unroll
  for (int n = 0; n < 4; ++n) {
    float te = beR[n] - d1R[n] - 2.0f * d2R[n] + 0.5f * e2R[n] + biasE;
    float s = 1.0f / (1.0f + expf(-te));
    seR[n] = s;
    atomicAdd(&aug[uR[n]], s);
    atomicAdd(&aug[vR[n]], s);
  }
  __syncthreads();

  // ---- rank-based top-256 (exact stable argsort(-aug)[:256]) ----
  {
    float a = aug[tid];
    int r = 0;
    #pragma unroll 8
    for (int j = 0; j < NNODE; ++j) {
      float b = aug[j];
      r += (b > a) || (b == a && j < tid);
    }
    maskS[tid] = (r < KEEPN) ? 1 : 0;
  }
  __syncthreads();
  ws[WS_SNW + roffN + tid] = snw_r * (float)maskS[tid];

  // ---- keep_e, klist compaction, degree count ----
  int* wsi = (int*)ws;
  #pragma unroll
  for (int n = 0; n < 4; ++n) {
    int e = tid + n * 512;
    int u = uR[n], v = vR[n];
    suv[e] = u | (v << 16);
    int k = maskS[u] & maskS[v];
    ws[WS_SEW + roffE + e] = seR[n] * (float)k;
    if (k) {
      int p = atomicAdd(kcp, 1);
      wsi[WS_KLIST + roffE + p] = e;
      atomicAdd(&degS[u], 1);
      atomicAdd(&degS[v], 1);
    }
  }
  __syncthreads();
  if (tid == 0) wsi[WS_KCNT + g] = *kcp;

  // ---- exclusive prefix of deg via wave scan ----
  int dv = degS[tid];
  int inc = dv;
  for (int o = 1; o < 64; o <<= 1) {
    int t = __shfl_up(inc, o, 64);
    if (lane >= o) inc += t;
  }
  if (lane == 63) iws[wid] = inc;
  __syncthreads();
  int base = 0;
  for (int k = 0; k < wid; ++k) base += iws[k];
  int myStart = base + inc - dv;
  offS[tid] = myStart;
  __syncthreads();

  // ---- CSR fill (ushort adjacency) ----
  for (int e = tid; e < EEDGE; e += 512) {
    int p2 = suv[e];
    int u = p2 & 0xffff, v = p2 >> 16;
    if (maskS[u] & maskS[v]) {
      int pu = atomicAdd(&offS[u], 1); adjU[pu] = (unsigned short)v;
      int pv = atomicAdd(&offS[v], 1); adjU[pv] = (unsigned short)u;
    }
  }
  __syncthreads();
  // after fill: offS[n] == end(n); degS[n] intact.

  // ---- WAVE 0 ONLY: barrier-free power iteration + Rayleigh ----
  if (wid == 0) {
    // register-cache per-lane node state (all indices compile-time constant
    // after full unroll -> stays in VGPRs, no scratch)
    int deg8[8], st8[8], ovf8 = 0;
    int nbf[8 * DCAP];
    #pragma unroll
    for (int j = 0; j < 8; ++j) {
      int n = lane + 64 * j;
      int end = offS[n];
      int dg = degS[n];
      int st = end - dg;
      deg8[j] = dg; st8[j] = st;
      if (dg > DCAP) ovf8 |= (1 << j);
      #pragma unroll
      for (int k = 0; k < DCAP; ++k)
        nbf[j * DCAP + k] = (k < dg) ? (int)adjU[st + k] : NNODE;
    }
    // init w (wave-local, in-order DS ops; no barrier needed)
    #pragma unroll
    for (int j = 0; j < 8; ++j) wvA[lane + 64 * j] = 0.04419417382415922f;
    if (lane == 0) { wvA[NNODE] = 0.f; wvB[NNODE] = 0.f; }

    for (int it = 0; it < PITERS; it += 2) {
      PSTEP(wvA, wvB, it);
      PSTEP(wvB, wvA, it + 1);
    }
    // Rayleigh quotient on wvA (iter 63 normalized)
    float pr = 0.f;
    #pragma unroll
    for (int j = 0; j < 8; ++j) {
      int n = lane + 64 * j;
      float a = (float)deg8[j] * wvA[n];
      #pragma unroll
      for (int k = 0; k < DCAP; ++k) a -= wvA[nbf[j * DCAP + k]];
      if (ovf8 & (1 << j))
        for (int p = st8[j] + DCAP; p < st8[j] + deg8[j]; ++p)
          a -= wvA[(int)adjU[p]];
      pr += wvA[n] * a;
    }
    for (int o = 32; o; o >>= 1) pr += __shfl_xor(pr, o, 64);
    if (lane == 0) ws[WS_SCALE + g] = 2.0f / (pr + 1e-12f);
  }
}

// ---------------------------------------------------------------------------
// K5: outputs. [0,512) xn dense; [512,2560) xe dense; [2560,2576) L0 scatter
// (g=0 zeroes the acc region first); [2576,6672) L1 pair enumeration.
__global__ __launch_bounds__(256) void k_out(
    const float* __restrict__ xn, const float* __restrict__ xe,
    const int* __restrict__ edge_u, const int* __restrict__ edge_v,
    const float* __restrict__ ws, float* __restrict__ out) {
  int b = blockIdx.x, tid = threadIdx.x;
  const int* wsi = (const int*)ws;
  if (b < 512) {
    int idx = b * 256 + tid;
    int row = idx >> 4;
    float s = ws[WS_SNW + row];
    float4 x4 = ((const float4*)xn)[idx];
    ((float4*)(out + O_XN))[idx] = make_float4(x4.x * s, x4.y * s, x4.z * s, x4.w * s);
  } else if (b < 2560) {
    int idx = (b - 512) * 256 + tid;
    int row = idx >> 4;
    float s = ws[WS_SEW + row];
    float4 x4 = ((const float4*)xe)[idx];
    ((float4*)(out + O_XE))[idx] = make_float4(x4.x * s, x4.y * s, x4.z * s, x4.w * s);
  } else if (b < 2576) {
    int g = b - 2560;
    if (g == 0) {
      // zero the MP accumulator scratch (riders skipped it); same-block
      // __syncthreads orders these stores before our atomics below.
      float4 z4 = make_float4(0.f, 0.f, 0.f, 0.f);
      float4* a4 = (float4*)(out + O_L0);
      for (int i = tid; i < AC_TOT4; i += 256) a4[i] = z4;
      __syncthreads();
    }
    int cnt = wsi[WS_KCNT + g];
    float s = ws[WS_SCALE + g];
    float* L0 = out + O_L0 + (long long)g * (NNODE * NNODE);
    const int* kl = wsi + WS_KLIST + g * EEDGE;
    const int* eu = edge_u + g * EEDGE;
    const int* ev = edge_v + g * EEDGE;
    for (int t = tid; t < cnt; t += 256) {
      int e = kl[t];
      int u = eu[e], v = ev[e];
      atomicAdd(&L0[u * NNODE + u], s);
      atomicAdd(&L0[v * NNODE + v], s);
      atomicAdd(&L0[u * NNODE + v], -s);
      atomicAdd(&L0[v * NNODE + u], -s);
    }
  } else {
    int q = b - 2576;
    int g = q >> 8, sb = q & 255;
    int cnt = wsi[WS_KCNT + g];
    float s = ws[WS_SCALE + g];
    float* L1 = out + O_L1 + (long long)g * (EEDGE * EEDGE);
    const int* kl = wsi + WS_KLIST + g * EEDGE;
    const int* eu = edge_u + g * EEDGE;
    const int* ev = edge_v + g * EEDGE;
    for (int a = sb; a < cnt; a += 256) {
      int e1 = kl[a];
      int u1 = eu[e1], v1 = ev[e1];
      long long rowoff = (long long)e1 * EEDGE;
      for (int b2 = tid; b2 < cnt; b2 += 256) {
        int e2 = kl[b2];
        int u2 = eu[e2], v2 = ev[e2];
        int val = (u1 == u2) + (v1 == v2) - (v1 == u2) - (u1 == v2);
        if (val) L1[rowoff + e2] = s * (float)val;
      }
    }
  }
}

// ---------------------------------------------------------------------------
extern "C" void kernel_launch(void* const* d_in, const int* in_sizes, int n_in,
                              void* d_out, int out_size, void* d_ws, size_t ws_size,
                              hipStream_t stream) {
  const float* x_n = (const float*)d_in[0];
  const float* x_e = (const float*)d_in[1];
  const int* edge_u = (const int*)d_in[2];
  const int* edge_v = (const int*)d_in[3];
  const int* src_n = (const int*)d_in[4];
  const int* dst_n = (const int*)d_in[5];
  const float* ew_n = (const float*)d_in[6];
  const int* src_e = (const int*)d_in[7];
  const int* dst_e = (const int*)d_in[8];
  const float* ew_e = (const float*)d_in[9];
  const float* W_n = (const float*)d_in[10];
  const float* b_n = (const float*)d_in[11];
  const float* W_e = (const float*)d_in[12];
  const float* b_e = (const float*)d_in[13];
  float* ws = (float*)d_ws;
  float* out = (float*)d_out;

  // K1: channel dots + zero MP accumulator scratch
  k_dots<<<1024 + 15, 512, 0, stream>>>(x_n, x_e, W_n, W_e, ws, out);
  // K2: MP hop 1 + zero riders (60 MB overlapped)
  k_mp1<<<384 + 640, 512, 0, stream>>>(src_n, dst_n, ew_n, src_e, dst_e, ew_e, ws, out);
  // K3: MP hop 2 + zero riders (60 MB overlapped)
  k_mp2<<<384 + 640, 512, 0, stream>>>(src_n, dst_n, ew_n, src_e, dst_e, ew_e, out);
  // K4: pool (scores/rank/CSR + wave-0 barrier-free power) + zero riders
  k_pool<<<16 + 2048, 512, 0, stream>>>(edge_u, edge_v, b_n, b_e, ws, out);
  // K5: dense xn/xe + sparse L0/L1 scatter (g=0 zeroes acc region first)
  k_out<<<6672, 256, 0, stream>>>(x_n, x_e, edge_u, edge_v, ws, out);
}

// Round 13
// 429.429 us; speedup vs baseline: 1.0794x; 1.0794x over previous
//
#include <hip/hip_runtime.h>
#include <math.h>

// Problem constants
#define GG 16
#define NNODE 512
#define EEDGE 2048
#define KEEPN 256
#define PITERS 64
#define NNT 8192    // G*N
#define NET 32768   // G*E

typedef float vfloat4 __attribute__((ext_vector_type(4)));

// workspace float offsets
#define WS_C1N 0        // c1 node (mp1 input; dead after mp1)
#define WS_C2N 8192
#define WS_BN  16384
#define WS_C1E 24576
#define WS_C2E 57344
#define WS_BE  90112
#define WS_SNW 122880   // masked node score (written by k_pool)
#define WS_SEW 131072   // masked edge score (written by k_pool)
#define WS_KLIST 163840 // int[32768]
#define WS_KCNT 196608  // int[16]
#define WS_SCALE 196624 // float[16]

// output float offsets: xn | L0 | xe | L1
#define O_XN 0
#define O_L0 524288
#define O_XE 4718592
#define O_L1 6815744

// MP accumulators in the L0 region of out (zeroed by k_dots riders, READ by
// k_pool workers; k_pool riders SKIP this region; k_out g=0 block zeroes it).
#define AC_D1N 0        // 8192
#define AC_D2N 8192     // 8192
#define AC_E2N 16384    // 8192
#define AC_D1E 24576    // 32768
#define AC_D2E 57344    // 32768
#define AC_E2E 90112    // 32768
#define AC_TOT4 30720   // 122880 floats / 4 (first 30720 f4 of L0)

// zero-space: float4 indices over concatenated L0 (1,048,576 f4) || L1
#define L04 1048576
#define ZTOT4 17825792   // 272 MiB

// DCAP=8: kept-subgraph degree ~Poisson(4); P(deg>8)~2% -> overflow loop is
// nearly never taken. Subtraction order stays CSR-order (regs cover first 8
// in order, overflow continues in order); padded slots subtract wcur[512]=0
// exactly -> bit-identical to DCAP=12, with 30% fewer LDS instructions.
#define DCAP 8

// ---------------------------------------------------------------------------
// K1: channel dots (1024 blocks) + zero MP accumulator scratch (15 blocks).
__global__ __launch_bounds__(512) void k_dots(
    const float* __restrict__ xn, const float* __restrict__ xe,
    const float* __restrict__ Wn, const float* __restrict__ We,
    float* __restrict__ ws, float* __restrict__ out) {
  const int tid = threadIdx.x, bid = blockIdx.x;
  if (bid >= 1024) {
    vfloat4 z = (vfloat4)(0.f);
    vfloat4* a4 = (vfloat4*)(out + O_L0);
    int base = (bid - 1024) * 512 + tid;        // 15*512 = 7680 threads
    #pragma unroll
    for (int k = 0; k < 4; ++k) a4[base + k * 7680] = z;  // 30720 f4 exact
    return;
  }
  const int lane = tid & 63;
  const int wv = (bid * 512 + tid) >> 6;   // 0..8191
  #pragma unroll
  for (int n = 0; n < 5; ++n) {
    int gw = wv + n * 8192;                // 0..40959
    const float* x; const float* W; int row; float *c1, *c2, *bs;
    if (gw < NNT) {
      row = gw; x = xn + (size_t)row * 64; W = Wn;
      c1 = ws + WS_C1N; c2 = ws + WS_C2N; bs = ws + WS_BN;
    } else {
      row = gw - NNT;
      x = xe + (size_t)row * 64; W = We;
      c1 = ws + WS_C1E; c2 = ws + WS_C2E; bs = ws + WS_BE;
    }
    float v = x[lane];
    float r0 = v * W[lane];
    float r1 = v * W[64 + lane];
    float r2 = v * W[128 + lane];
    for (int o = 32; o; o >>= 1) {
      r0 += __shfl_xor(r0, o, 64);
      r1 += __shfl_xor(r1, o, 64);
      r2 += __shfl_xor(r2, o, 64);
    }
    if (lane == 0) { c1[row] = r1; c2[row] = r2; bs[row] = r0 + r1 + r2; }
  }
}

// ---------------------------------------------------------------------------
// K2: MP hop 1 (wide, 384 blocks): d1 += w*c1[s], d2 += w*c2[s], global atomics.
__global__ __launch_bounds__(512) void k_mp1(
    const int* __restrict__ src_n, const int* __restrict__ dst_n, const float* __restrict__ wn,
    const int* __restrict__ src_e, const int* __restrict__ dst_e, const float* __restrict__ we,
    const float* __restrict__ ws, float* __restrict__ out) {
  int gid = blockIdx.x * 512 + threadIdx.x;    // [0, 196608)
  float* acc = (float*)(out + O_L0);
  if (gid < 65536) {
    int s = src_n[gid], d = dst_n[gid]; float w = wn[gid];
    atomicAdd(&acc[AC_D1N + d], w * ws[WS_C1N + s]);
    atomicAdd(&acc[AC_D2N + d], w * ws[WS_C2N + s]);
  } else {
    int e = gid - 65536;                        // [0, 131072)
    int s = src_e[e], d = dst_e[e]; float w = we[e];
    atomicAdd(&acc[AC_D1E + d], w * ws[WS_C1E + s]);
    atomicAdd(&acc[AC_D2E + d], w * ws[WS_C2E + s]);
  }
}

// ---------------------------------------------------------------------------
// K3: MP hop 2 (wide): e2 += w*d2[s].
__global__ __launch_bounds__(512) void k_mp2(
    const int* __restrict__ src_n, const int* __restrict__ dst_n, const float* __restrict__ wn,
    const int* __restrict__ src_e, const int* __restrict__ dst_e, const float* __restrict__ we,
    float* __restrict__ out) {
  int gid = blockIdx.x * 512 + threadIdx.x;    // [0, 196608)
  float* acc = (float*)(out + O_L0);
  if (gid < 65536) {
    int s = src_n[gid], d = dst_n[gid]; float w = wn[gid];
    atomicAdd(&acc[AC_E2N + d], w * acc[AC_D2N + s]);
  } else {
    int e = gid - 65536;
    int s = src_e[e], d = dst_e[e]; float w = we[e];
    atomicAdd(&acc[AC_E2E + d], w * acc[AC_D2E + s]);
  }
}

// ---------------------------------------------------------------------------
// K4: pool. Workers (blocks 0..15): scores + aug + rank + compact + CSR +
// gather-based 8-wave power (R8/R10 structure, DCAP=8). Riders (16..2063):
// zero L0+L1 EXCEPT the acc region.
#define PM_AUG  0       // 512 f
#define PM_RED  512     // 8 f
#define PM_IWS  520     // 8 int
#define PM_KCP  528     // 1 int
#define PM_MASK 544     // 512 int
#define PM_DEG  1056    // 512 int
#define PM_OFF  1568    // 512 int
#define PM_SUV  2080    // 2048 int
#define PM_ADJ  4128    // 2048 f (4096 ushorts)
#define PM_WVA  6176    // 513 f
#define PM_WVB  6692    // 513 f
#define PM_TOT  7208
__global__ __launch_bounds__(512, 2) void k_pool(
    const int* __restrict__ edge_u, const int* __restrict__ edge_v,
    const float* __restrict__ bnp, const float* __restrict__ bep,
    float* __restrict__ ws, float* __restrict__ out) {
  const int tid = threadIdx.x;
  if (blockIdx.x >= 16) {
    vfloat4 z = (vfloat4)(0.f);
    vfloat4* o4 = (vfloat4*)out;
    int base = (blockIdx.x - 16) * 512 + tid;
    #pragma unroll
    for (int n = 0; n < 17; ++n) {     // covers [AC_TOT4, ZTOT4) exactly
      int i = AC_TOT4 + base + n * 1048576;
      if (i < ZTOT4) {
        int f = (i < L04) ? (O_L0 / 4 + i) : (O_L1 / 4 + (i - L04));
        __builtin_nontemporal_store(z, &o4[f]);
      }
    }
    return;
  }
  __shared__ float smem[PM_TOT];
  int* smi = (int*)smem;
  float* aug = smem + PM_AUG;
  float* red = smem + PM_RED;
  int* iws   = smi + PM_IWS;
  int* kcp   = smi + PM_KCP;
  int* maskS = smi + PM_MASK;
  int* degS  = smi + PM_DEG;
  int* offS  = smi + PM_OFF;
  int* suv   = smi + PM_SUV;
  unsigned short* adjU = (unsigned short*)(smi + PM_ADJ);
  float* wvA = smem + PM_WVA;
  float* wvB = smem + PM_WVB;

  const int g = blockIdx.x;
  const int roffN = g * NNODE;
  const int roffE = g * EEDGE;
  const int lane = tid & 63, wid = tid >> 6;
  const float* acc = (const float*)(out + O_L0);
  float biasN = bnp[0], biasE = bep[0];

  // ---- batched global loads for score phase ----
  float bn  = ws[WS_BN + roffN + tid];
  float nd1 = acc[AC_D1N + roffN + tid];
  float nd2 = acc[AC_D2N + roffN + tid];
  float ne2 = acc[AC_E2N + roffN + tid];
  float beR[4], d1R[4], d2R[4], e2R[4]; int uR[4], vR[4];
  #pragma unroll
  for (int n = 0; n < 4; ++n) {
    int e = roffE + tid + n * 512;
    beR[n] = ws[WS_BE + e];
    d1R[n] = acc[AC_D1E + e];
    d2R[n] = acc[AC_D2E + e];
    e2R[n] = acc[AC_E2E + e];
    uR[n] = edge_u[e];
    vR[n] = edge_v[e];
  }

  // ---- node score -> aug init ----
  float tn = bn - nd1 - 2.0f * nd2 + 0.5f * ne2 + biasN;
  float snw_r = 1.0f / (1.0f + expf(-tn));
  aug[tid] = snw_r;
  degS[tid] = 0;
  if (tid == 0) *kcp = 0;
  __syncthreads();

  // ---- edge scores -> aug atomics (LDS) ----
  float seR[4];
  #pragma unroll
  for (int n = 0; n < 4; ++n) {
    float te = beR[n] - d1R[n] - 2.0f * d2R[n] + 0.5f * e2R[n] + biasE;
    float s = 1.0f / (1.0f + expf(-te));
    seR[n] = s;
    atomicAdd(&aug[uR[n]], s);
    atomicAdd(&aug[vR[n]], s);
  }
  __syncthreads();

  // ---- rank-based top-256 (exact stable argsort(-aug)[:256]) ----
  {
    float a = aug[tid];
    int r = 0;
    #pragma unroll 8
    for (int j = 0; j < NNODE; ++j) {
      float b = aug[j];
      r += (b > a) || (b == a && j < tid);
    }
    maskS[tid] = (r < KEEPN) ? 1 : 0;
  }
  __syncthreads();
  ws[WS_SNW + roffN + tid] = snw_r * (float)maskS[tid];

  // ---- keep_e, klist compaction, degree count ----
  int* wsi = (int*)ws;
  #pragma unroll
  for (int n = 0; n < 4; ++n) {
    int e = tid + n * 512;
    int u = uR[n], v = vR[n];
    suv[e] = u | (v << 16);
    int k = maskS[u] & maskS[v];
    ws[WS_SEW + roffE + e] = seR[n] * (float)k;
    if (k) {
      int p = atomicAdd(kcp, 1);
      wsi[WS_KLIST + roffE + p] = e;
      atomicAdd(&degS[u], 1);
      atomicAdd(&degS[v], 1);
    }
  }
  __syncthreads();
  if (tid == 0) wsi[WS_KCNT + g] = *kcp;

  // ---- exclusive prefix of deg via wave scan ----
  int dv = degS[tid];
  int inc = dv;
  for (int o = 1; o < 64; o <<= 1) {
    int t = __shfl_up(inc, o, 64);
    if (lane >= o) inc += t;
  }
  if (lane == 63) iws[wid] = inc;
  __syncthreads();
  int base = 0;
  for (int k = 0; k < wid; ++k) base += iws[k];
  int myStart = base + inc - dv;
  offS[tid] = myStart;
  __syncthreads();

  // ---- CSR fill (ushort adjacency) ----
  for (int e = tid; e < EEDGE; e += 512) {
    int p2 = suv[e];
    int u = p2 & 0xffff, v = p2 >> 16;
    if (maskS[u] & maskS[v]) {
      int pu = atomicAdd(&offS[u], 1); adjU[pu] = (unsigned short)v;
      int pv = atomicAdd(&offS[v], 1); adjU[pv] = (unsigned short)u;
    }
  }
  __syncthreads();
  int myDeg = dv;
  int myEnd = myStart + myDeg;

  // ---- register-cached adjacency (pad -> pinned zero cell 512) ----
  int nbr[DCAP];
  #pragma unroll
  for (int k = 0; k < DCAP; ++k)
    nbr[k] = (k < myDeg) ? (int)adjU[myStart + k] : NNODE;
  bool ovf = myDeg > DCAP;

  wvA[tid] = 0.04419417382415922f; // 1/sqrt(512)
  if (tid == 0) { wvA[NNODE] = 0.f; wvB[NNODE] = 0.f; }
  __syncthreads();
  float* wcur = wvA; float* wnext = wvB;
  for (int it = 0; it < PITERS; ++it) {
    float tg[DCAP];
    #pragma unroll
    for (int k = 0; k < DCAP; ++k) tg[k] = wcur[nbr[k]];
    float acc2 = (float)myDeg * wcur[tid];
    #pragma unroll
    for (int k = 0; k < DCAP; ++k) acc2 -= tg[k];
    if (ovf) for (int p = myStart + DCAP; p < myEnd; ++p) acc2 -= wcur[(int)adjU[p]];
    if ((it & 7) == 7) {
      float sq = acc2 * acc2;
      for (int o = 32; o; o >>= 1) sq += __shfl_xor(sq, o, 64);
      if (lane == 0) red[wid] = sq;
      __syncthreads();
      float tot = red[0] + red[1] + red[2] + red[3]
                + red[4] + red[5] + red[6] + red[7];
      wnext[tid] = acc2 * (1.0f / (sqrtf(tot) + 1e-12f));
    } else {
      wnext[tid] = acc2;
    }
    __syncthreads();
    float* tmp = wcur; wcur = wnext; wnext = tmp;
  }
  // ---- Rayleigh quotient (iter 63 normalized) ----
  {
    float tg[DCAP];
    #pragma unroll
    for (int k = 0; k < DCAP; ++k) tg[k] = wcur[nbr[k]];
    float wv_ = wcur[tid];
    float acc2 = (float)myDeg * wv_;
    #pragma unroll
    for (int k = 0; k < DCAP; ++k) acc2 -= tg[k];
    if (ovf) for (int p = myStart + DCAP; p < myEnd; ++p) acc2 -= wcur[(int)adjU[p]];
    float pr = wv_ * acc2;
    for (int o = 32; o; o >>= 1) pr += __shfl_xor(pr, o, 64);
    if (lane == 0) red[wid] = pr;
    __syncthreads();
    if (tid == 0) {
      float lam = red[0] + red[1] + red[2] + red[3]
                + red[4] + red[5] + red[6] + red[7];
      ws[WS_SCALE + g] = 2.0f / (lam + 1e-12f);
    }
  }
}

// ---------------------------------------------------------------------------
// K5: outputs. [0,512) xn dense; [512,2560) xe dense; [2560,2576) L0 scatter
// (g=0 zeroes the acc region first); [2576,6672) L1 pair enumeration.
__global__ __launch_bounds__(256) void k_out(
    const float* __restrict__ xn, const float* __restrict__ xe,
    const int* __restrict__ edge_u, const int* __restrict__ edge_v,
    const float* __restrict__ ws, float* __restrict__ out) {
  int b = blockIdx.x, tid = threadIdx.x;
  const int* wsi = (const int*)ws;
  if (b < 512) {
    int idx = b * 256 + tid;
    int row = idx >> 4;
    float s = ws[WS_SNW + row];
    float4 x4 = ((const float4*)xn)[idx];
    ((float4*)(out + O_XN))[idx] = make_float4(x4.x * s, x4.y * s, x4.z * s, x4.w * s);
  } else if (b < 2560) {
    int idx = (b - 512) * 256 + tid;
    int row = idx >> 4;
    float s = ws[WS_SEW + row];
    float4 x4 = ((const float4*)xe)[idx];
    ((float4*)(out + O_XE))[idx] = make_float4(x4.x * s, x4.y * s, x4.z * s, x4.w * s);
  } else if (b < 2576) {
    int g = b - 2560;
    if (g == 0) {
      // zero the MP accumulator scratch (riders skipped it); same-block
      // __syncthreads orders these stores before our atomics below.
      float4 z4 = make_float4(0.f, 0.f, 0.f, 0.f);
      float4* a4 = (float4*)(out + O_L0);
      for (int i = tid; i < AC_TOT4; i += 256) a4[i] = z4;
      __syncthreads();
    }
    int cnt = wsi[WS_KCNT + g];
    float s = ws[WS_SCALE + g];
    float* L0 = out + O_L0 + (long long)g * (NNODE * NNODE);
    const int* kl = wsi + WS_KLIST + g * EEDGE;
    const int* eu = edge_u + g * EEDGE;
    const int* ev = edge_v + g * EEDGE;
    for (int t = tid; t < cnt; t += 256) {
      int e = kl[t];
      int u = eu[e], v = ev[e];
      atomicAdd(&L0[u * NNODE + u], s);
      atomicAdd(&L0[v * NNODE + v], s);
      atomicAdd(&L0[u * NNODE + v], -s);
      atomicAdd(&L0[v * NNODE + u], -s);
    }
  } else {
    int q = b - 2576;
    int g = q >> 8, sb = q & 255;
    int cnt = wsi[WS_KCNT + g];
    float s = ws[WS_SCALE + g];
    float* L1 = out + O_L1 + (long long)g * (EEDGE * EEDGE);
    const int* kl = wsi + WS_KLIST + g * EEDGE;
    const int* eu = edge_u + g * EEDGE;
    const int* ev = edge_v + g * EEDGE;
    for (int a = sb; a < cnt; a += 256) {
      int e1 = kl[a];
      int u1 = eu[e1], v1 = ev[e1];
      long long rowoff = (long long)e1 * EEDGE;
      for (int b2 = tid; b2 < cnt; b2 += 256) {
        int e2 = kl[b2];
        int u2 = eu[e2], v2 = ev[e2];
        int val = (u1 == u2) + (v1 == v2) - (v1 == u2) - (u1 == v2);
        if (val) L1[rowoff + e2] = s * (float)val;
      }
    }
  }
}

// ---------------------------------------------------------------------------
extern "C" void kernel_launch(void* const* d_in, const int* in_sizes, int n_in,
                              void* d_out, int out_size, void* d_ws, size_t ws_size,
                              hipStream_t stream) {
  const float* x_n = (const float*)d_in[0];
  const float* x_e = (const float*)d_in[1];
  const int* edge_u = (const int*)d_in[2];
  const int* edge_v = (const int*)d_in[3];
  const int* src_n = (const int*)d_in[4];
  const int* dst_n = (const int*)d_in[5];
  const float* ew_n = (const float*)d_in[6];
  const int* src_e = (const int*)d_in[7];
  const int* dst_e = (const int*)d_in[8];
  const float* ew_e = (const float*)d_in[9];
  const float* W_n = (const float*)d_in[10];
  const float* b_n = (const float*)d_in[11];
  const float* W_e = (const float*)d_in[12];
  const float* b_e = (const float*)d_in[13];
  float* ws = (float*)d_ws;
  float* out = (float*)d_out;

  // K1: channel dots + zero MP accumulator scratch
  k_dots<<<1024 + 15, 512, 0, stream>>>(x_n, x_e, W_n, W_e, ws, out);
  // K2: MP hop 1 (wide, global atomics)
  k_mp1<<<384, 512, 0, stream>>>(src_n, dst_n, ew_n, src_e, dst_e, ew_e, ws, out);
  // K3: MP hop 2 (wide)
  k_mp2<<<384, 512, 0, stream>>>(src_n, dst_n, ew_n, src_e, dst_e, ew_e, out);
  // K4: pool (scores/rank/CSR + 8-wave DCAP=8 power) + zero riders (skip acc)
  k_pool<<<16 + 2048, 512, 0, stream>>>(edge_u, edge_v, b_n, b_e, ws, out);
  // K5: dense xn/xe + sparse L0/L1 scatter (g=0 zeroes acc region first)
  k_out<<<6672, 256, 0, stream>>>(x_n, x_e, edge_u, edge_v, ws, out);
}

// Round 14
// 415.125 us; speedup vs baseline: 1.1166x; 1.0345x over previous
//
#include <hip/hip_runtime.h>
#include <math.h>

// Problem constants
#define GG 16
#define NNODE 512
#define EEDGE 2048
#define KEEPN 256
#define PITERS 64
#define NNT 8192    // G*N
#define NET 32768   // G*E

typedef float vfloat4 __attribute__((ext_vector_type(4)));

// workspace float offsets
#define WS_C1N 0        // c1 node (mp1 input; dead after mp1)
#define WS_C2N 8192
#define WS_BN  16384
#define WS_C1E 24576
#define WS_C2E 57344
#define WS_BE  90112
#define WS_SNW 122880   // masked node score (written by k_pool)
#define WS_SEW 131072   // masked edge score (written by k_pool)
#define WS_KLIST 163840 // int[32768]
#define WS_KCNT 196608  // int[16]
#define WS_SCALE 196624 // float[16]

// output float offsets: xn | L0 | xe | L1
#define O_XN 0
#define O_L0 524288
#define O_XE 4718592
#define O_L1 6815744

// MP accumulators in the L0 region of out (zeroed by k_dots riders, READ by
// k_pool workers; k_pool riders SKIP this region; k_out g=0 block zeroes it).
#define AC_D1N 0        // 8192
#define AC_D2N 8192     // 8192
#define AC_E2N 16384    // 8192
#define AC_D1E 24576    // 32768
#define AC_D2E 57344    // 32768
#define AC_E2E 90112    // 32768
#define AC_TOT4 30720   // 122880 floats / 4 (first 30720 f4 of L0)

// zero-space: float4 indices over concatenated L0 (1,048,576 f4) || L1
#define L04 1048576
#define ZTOT4 17825792   // 272 MiB

#define DCAP 12

// ---------------------------------------------------------------------------
// K1: channel dots (1024 blocks) + zero MP accumulator scratch (15 blocks).
__global__ __launch_bounds__(512) void k_dots(
    const float* __restrict__ xn, const float* __restrict__ xe,
    const float* __restrict__ Wn, const float* __restrict__ We,
    float* __restrict__ ws, float* __restrict__ out) {
  const int tid = threadIdx.x, bid = blockIdx.x;
  if (bid >= 1024) {
    vfloat4 z = (vfloat4)(0.f);
    vfloat4* a4 = (vfloat4*)(out + O_L0);
    int base = (bid - 1024) * 512 + tid;        // 15*512 = 7680 threads
    #pragma unroll
    for (int k = 0; k < 4; ++k) a4[base + k * 7680] = z;  // 30720 f4 exact
    return;
  }
  const int lane = tid & 63;
  const int wv = (bid * 512 + tid) >> 6;   // 0..8191
  #pragma unroll
  for (int n = 0; n < 5; ++n) {
    int gw = wv + n * 8192;                // 0..40959
    const float* x; const float* W; int row; float *c1, *c2, *bs;
    if (gw < NNT) {
      row = gw; x = xn + (size_t)row * 64; W = Wn;
      c1 = ws + WS_C1N; c2 = ws + WS_C2N; bs = ws + WS_BN;
    } else {
      row = gw - NNT;
      x = xe + (size_t)row * 64; W = We;
      c1 = ws + WS_C1E; c2 = ws + WS_C2E; bs = ws + WS_BE;
    }
    float v = x[lane];
    float r0 = v * W[lane];
    float r1 = v * W[64 + lane];
    float r2 = v * W[128 + lane];
    for (int o = 32; o; o >>= 1) {
      r0 += __shfl_xor(r0, o, 64);
      r1 += __shfl_xor(r1, o, 64);
      r2 += __shfl_xor(r2, o, 64);
    }
    if (lane == 0) { c1[row] = r1; c2[row] = r2; bs[row] = r0 + r1 + r2; }
  }
}

// ---------------------------------------------------------------------------
// K2: MP hop 1 (wide, 384 blocks): d1 += w*c1[s], d2 += w*c2[s], global atomics.
__global__ __launch_bounds__(512) void k_mp1(
    const int* __restrict__ src_n, const int* __restrict__ dst_n, const float* __restrict__ wn,
    const int* __restrict__ src_e, const int* __restrict__ dst_e, const float* __restrict__ we,
    const float* __restrict__ ws, float* __restrict__ out) {
  int gid = blockIdx.x * 512 + threadIdx.x;    // [0, 196608)
  float* acc = (float*)(out + O_L0);
  if (gid < 65536) {
    int s = src_n[gid], d = dst_n[gid]; float w = wn[gid];
    atomicAdd(&acc[AC_D1N + d], w * ws[WS_C1N + s]);
    atomicAdd(&acc[AC_D2N + d], w * ws[WS_C2N + s]);
  } else {
    int e = gid - 65536;                        // [0, 131072)
    int s = src_e[e], d = dst_e[e]; float w = we[e];
    atomicAdd(&acc[AC_D1E + d], w * ws[WS_C1E + s]);
    atomicAdd(&acc[AC_D2E + d], w * ws[WS_C2E + s]);
  }
}

// ---------------------------------------------------------------------------
// K3: MP hop 2 (wide): e2 += w*d2[s].
__global__ __launch_bounds__(512) void k_mp2(
    const int* __restrict__ src_n, const int* __restrict__ dst_n, const float* __restrict__ wn,
    const int* __restrict__ src_e, const int* __restrict__ dst_e, const float* __restrict__ we,
    float* __restrict__ out) {
  int gid = blockIdx.x * 512 + threadIdx.x;    // [0, 196608)
  float* acc = (float*)(out + O_L0);
  if (gid < 65536) {
    int s = src_n[gid], d = dst_n[gid]; float w = wn[gid];
    atomicAdd(&acc[AC_E2N + d], w * acc[AC_D2N + s]);
  } else {
    int e = gid - 65536;
    int s = src_e[e], d = dst_e[e]; float w = we[e];
    atomicAdd(&acc[AC_E2E + d], w * acc[AC_D2E + s]);
  }
}

// ---------------------------------------------------------------------------
// K4: pool. Workers (blocks 0..15): scores + aug + rank + compact + CSR +
// gather-based 8-wave power (DCAP=12 — empirical optimum; R9/R11/R12/R13
// variants all null or negative). Riders (16..2063): zero L0+L1 except acc.
#define PM_AUG  0       // 512 f
#define PM_RED  512     // 8 f
#define PM_IWS  520     // 8 int
#define PM_KCP  528     // 1 int
#define PM_MASK 544     // 512 int
#define PM_DEG  1056    // 512 int
#define PM_OFF  1568    // 512 int
#define PM_SUV  2080    // 2048 int
#define PM_ADJ  4128    // 2048 f (4096 ushorts)
#define PM_WVA  6176    // 513 f
#define PM_WVB  6692    // 513 f
#define PM_TOT  7208
__global__ __launch_bounds__(512, 2) void k_pool(
    const int* __restrict__ edge_u, const int* __restrict__ edge_v,
    const float* __restrict__ bnp, const float* __restrict__ bep,
    float* __restrict__ ws, float* __restrict__ out) {
  const int tid = threadIdx.x;
  if (blockIdx.x >= 16) {
    vfloat4 z = (vfloat4)(0.f);
    vfloat4* o4 = (vfloat4*)out;
    int base = (blockIdx.x - 16) * 512 + tid;
    #pragma unroll
    for (int n = 0; n < 17; ++n) {     // covers [AC_TOT4, ZTOT4) exactly
      int i = AC_TOT4 + base + n * 1048576;
      if (i < ZTOT4) {
        int f = (i < L04) ? (O_L0 / 4 + i) : (O_L1 / 4 + (i - L04));
        __builtin_nontemporal_store(z, &o4[f]);
      }
    }
    return;
  }
  __shared__ float smem[PM_TOT];
  int* smi = (int*)smem;
  float* aug = smem + PM_AUG;
  float* red = smem + PM_RED;
  int* iws   = smi + PM_IWS;
  int* kcp   = smi + PM_KCP;
  int* maskS = smi + PM_MASK;
  int* degS  = smi + PM_DEG;
  int* offS  = smi + PM_OFF;
  int* suv   = smi + PM_SUV;
  unsigned short* adjU = (unsigned short*)(smi + PM_ADJ);
  float* wvA = smem + PM_WVA;
  float* wvB = smem + PM_WVB;

  const int g = blockIdx.x;
  const int roffN = g * NNODE;
  const int roffE = g * EEDGE;
  const int lane = tid & 63, wid = tid >> 6;
  const float* acc = (const float*)(out + O_L0);
  float biasN = bnp[0], biasE = bep[0];

  // ---- batched global loads for score phase ----
  float bn  = ws[WS_BN + roffN + tid];
  float nd1 = acc[AC_D1N + roffN + tid];
  float nd2 = acc[AC_D2N + roffN + tid];
  float ne2 = acc[AC_E2N + roffN + tid];
  float beR[4], d1R[4], d2R[4], e2R[4]; int uR[4], vR[4];
  #pragma unroll
  for (int n = 0; n < 4; ++n) {
    int e = roffE + tid + n * 512;
    beR[n] = ws[WS_BE + e];
    d1R[n] = acc[AC_D1E + e];
    d2R[n] = acc[AC_D2E + e];
    e2R[n] = acc[AC_E2E + e];
    uR[n] = edge_u[e];
    vR[n] = edge_v[e];
  }

  // ---- node score -> aug init ----
  float tn = bn - nd1 - 2.0f * nd2 + 0.5f * ne2 + biasN;
  float snw_r = 1.0f / (1.0f + expf(-tn));
  aug[tid] = snw_r;
  degS[tid] = 0;
  if (tid == 0) *kcp = 0;
  __syncthreads();

  // ---- edge scores -> aug atomics (LDS) ----
  float seR[4];
  #pragma unroll
  for (int n = 0; n < 4; ++n) {
    float te = beR[n] - d1R[n] - 2.0f * d2R[n] + 0.5f * e2R[n] + biasE;
    float s = 1.0f / (1.0f + expf(-te));
    seR[n] = s;
    atomicAdd(&aug[uR[n]], s);
    atomicAdd(&aug[vR[n]], s);
  }
  __syncthreads();

  // ---- rank-based top-256 (exact stable argsort(-aug)[:256]) ----
  {
    float a = aug[tid];
    int r = 0;
    #pragma unroll 8
    for (int j = 0; j < NNODE; ++j) {
      float b = aug[j];
      r += (b > a) || (b == a && j < tid);
    }
    maskS[tid] = (r < KEEPN) ? 1 : 0;
  }
  __syncthreads();
  ws[WS_SNW + roffN + tid] = snw_r * (float)maskS[tid];

  // ---- keep_e, klist compaction, degree count ----
  int* wsi = (int*)ws;
  #pragma unroll
  for (int n = 0; n < 4; ++n) {
    int e = tid + n * 512;
    int u = uR[n], v = vR[n];
    suv[e] = u | (v << 16);
    int k = maskS[u] & maskS[v];
    ws[WS_SEW + roffE + e] = seR[n] * (float)k;
    if (k) {
      int p = atomicAdd(kcp, 1);
      wsi[WS_KLIST + roffE + p] = e;
      atomicAdd(&degS[u], 1);
      atomicAdd(&degS[v], 1);
    }
  }
  __syncthreads();
  if (tid == 0) wsi[WS_KCNT + g] = *kcp;

  // ---- exclusive prefix of deg via wave scan ----
  int dv = degS[tid];
  int inc = dv;
  for (int o = 1; o < 64; o <<= 1) {
    int t = __shfl_up(inc, o, 64);
    if (lane >= o) inc += t;
  }
  if (lane == 63) iws[wid] = inc;
  __syncthreads();
  int base = 0;
  for (int k = 0; k < wid; ++k) base += iws[k];
  int myStart = base + inc - dv;
  offS[tid] = myStart;
  __syncthreads();

  // ---- CSR fill (ushort adjacency) ----
  for (int e = tid; e < EEDGE; e += 512) {
    int p2 = suv[e];
    int u = p2 & 0xffff, v = p2 >> 16;
    if (maskS[u] & maskS[v]) {
      int pu = atomicAdd(&offS[u], 1); adjU[pu] = (unsigned short)v;
      int pv = atomicAdd(&offS[v], 1); adjU[pv] = (unsigned short)u;
    }
  }
  __syncthreads();
  int myDeg = dv;
  int myEnd = myStart + myDeg;

  // ---- register-cached adjacency (pad -> pinned zero cell 512) ----
  int nbr[DCAP];
  #pragma unroll
  for (int k = 0; k < DCAP; ++k)
    nbr[k] = (k < myDeg) ? (int)adjU[myStart + k] : NNODE;
  bool ovf = myDeg > DCAP;

  wvA[tid] = 0.04419417382415922f; // 1/sqrt(512)
  if (tid == 0) { wvA[NNODE] = 0.f; wvB[NNODE] = 0.f; }
  __syncthreads();
  float* wcur = wvA; float* wnext = wvB;
  for (int it = 0; it < PITERS; ++it) {
    float tg[DCAP];
    #pragma unroll
    for (int k = 0; k < DCAP; ++k) tg[k] = wcur[nbr[k]];
    float acc2 = (float)myDeg * wcur[tid];
    #pragma unroll
    for (int k = 0; k < DCAP; ++k) acc2 -= tg[k];
    if (ovf) for (int p = myStart + DCAP; p < myEnd; ++p) acc2 -= wcur[(int)adjU[p]];
    if ((it & 7) == 7) {
      float sq = acc2 * acc2;
      for (int o = 32; o; o >>= 1) sq += __shfl_xor(sq, o, 64);
      if (lane == 0) red[wid] = sq;
      __syncthreads();
      float tot = red[0] + red[1] + red[2] + red[3]
                + red[4] + red[5] + red[6] + red[7];
      wnext[tid] = acc2 * (1.0f / (sqrtf(tot) + 1e-12f));
    } else {
      wnext[tid] = acc2;
    }
    __syncthreads();
    float* tmp = wcur; wcur = wnext; wnext = tmp;
  }
  // ---- Rayleigh quotient (iter 63 normalized) ----
  {
    float tg[DCAP];
    #pragma unroll
    for (int k = 0; k < DCAP; ++k) tg[k] = wcur[nbr[k]];
    float wv_ = wcur[tid];
    float acc2 = (float)myDeg * wv_;
    #pragma unroll
    for (int k = 0; k < DCAP; ++k) acc2 -= tg[k];
    if (ovf) for (int p = myStart + DCAP; p < myEnd; ++p) acc2 -= wcur[(int)adjU[p]];
    float pr = wv_ * acc2;
    for (int o = 32; o; o >>= 1) pr += __shfl_xor(pr, o, 64);
    if (lane == 0) red[wid] = pr;
    __syncthreads();
    if (tid == 0) {
      float lam = red[0] + red[1] + red[2] + red[3]
                + red[4] + red[5] + red[6] + red[7];
      ws[WS_SCALE + g] = 2.0f / (lam + 1e-12f);
    }
  }
}

// ---------------------------------------------------------------------------
// K5: outputs. [0,512) xn dense; [512,2560) xe dense; [2560,2576) L0 scatter
// (g=0 zeroes the acc region first); [2576,6672) L1 pair enumeration.
__global__ __launch_bounds__(256) void k_out(
    const float* __restrict__ xn, const float* __restrict__ xe,
    const int* __restrict__ edge_u, const int* __restrict__ edge_v,
    const float* __restrict__ ws, float* __restrict__ out) {
  int b = blockIdx.x, tid = threadIdx.x;
  const int* wsi = (const int*)ws;
  if (b < 512) {
    int idx = b * 256 + tid;
    int row = idx >> 4;
    float s = ws[WS_SNW + row];
    float4 x4 = ((const float4*)xn)[idx];
    ((float4*)(out + O_XN))[idx] = make_float4(x4.x * s, x4.y * s, x4.z * s, x4.w * s);
  } else if (b < 2560) {
    int idx = (b - 512) * 256 + tid;
    int row = idx >> 4;
    float s = ws[WS_SEW + row];
    float4 x4 = ((const float4*)xe)[idx];
    ((float4*)(out + O_XE))[idx] = make_float4(x4.x * s, x4.y * s, x4.z * s, x4.w * s);
  } else if (b < 2576) {
    int g = b - 2560;
    if (g == 0) {
      // zero the MP accumulator scratch (riders skipped it); same-block
      // __syncthreads orders these stores before our atomics below.
      float4 z4 = make_float4(0.f, 0.f, 0.f, 0.f);
      float4* a4 = (float4*)(out + O_L0);
      for (int i = tid; i < AC_TOT4; i += 256) a4[i] = z4;
      __syncthreads();
    }
    int cnt = wsi[WS_KCNT + g];
    float s = ws[WS_SCALE + g];
    float* L0 = out + O_L0 + (long long)g * (NNODE * NNODE);
    const int* kl = wsi + WS_KLIST + g * EEDGE;
    const int* eu = edge_u + g * EEDGE;
    const int* ev = edge_v + g * EEDGE;
    for (int t = tid; t < cnt; t += 256) {
      int e = kl[t];
      int u = eu[e], v = ev[e];
      atomicAdd(&L0[u * NNODE + u], s);
      atomicAdd(&L0[v * NNODE + v], s);
      atomicAdd(&L0[u * NNODE + v], -s);
      atomicAdd(&L0[v * NNODE + u], -s);
    }
  } else {
    int q = b - 2576;
    int g = q >> 8, sb = q & 255;
    int cnt = wsi[WS_KCNT + g];
    float s = ws[WS_SCALE + g];
    float* L1 = out + O_L1 + (long long)g * (EEDGE * EEDGE);
    const int* kl = wsi + WS_KLIST + g * EEDGE;
    const int* eu = edge_u + g * EEDGE;
    const int* ev = edge_v + g * EEDGE;
    for (int a = sb; a < cnt; a += 256) {
      int e1 = kl[a];
      int u1 = eu[e1], v1 = ev[e1];
      long long rowoff = (long long)e1 * EEDGE;
      for (int b2 = tid; b2 < cnt; b2 += 256) {
        int e2 = kl[b2];
        int u2 = eu[e2], v2 = ev[e2];
        int val = (u1 == u2) + (v1 == v2) - (v1 == u2) - (u1 == v2);
        if (val) L1[rowoff + e2] = s * (float)val;
      }
    }
  }
}

// ---------------------------------------------------------------------------
extern "C" void kernel_launch(void* const* d_in, const int* in_sizes, int n_in,
                              void* d_out, int out_size, void* d_ws, size_t ws_size,
                              hipStream_t stream) {
  const float* x_n = (const float*)d_in[0];
  const float* x_e = (const float*)d_in[1];
  const int* edge_u = (const int*)d_in[2];
  const int* edge_v = (const int*)d_in[3];
  const int* src_n = (const int*)d_in[4];
  const int* dst_n = (const int*)d_in[5];
  const float* ew_n = (const float*)d_in[6];
  const int* src_e = (const int*)d_in[7];
  const int* dst_e = (const int*)d_in[8];
  const float* ew_e = (const float*)d_in[9];
  const float* W_n = (const float*)d_in[10];
  const float* b_n = (const float*)d_in[11];
  const float* W_e = (const float*)d_in[12];
  const float* b_e = (const float*)d_in[13];
  float* ws = (float*)d_ws;
  float* out = (float*)d_out;

  // K1: channel dots + zero MP accumulator scratch
  k_dots<<<1024 + 15, 512, 0, stream>>>(x_n, x_e, W_n, W_e, ws, out);
  // K2: MP hop 1 (wide, global atomics)
  k_mp1<<<384, 512, 0, stream>>>(src_n, dst_n, ew_n, src_e, dst_e, ew_e, ws, out);
  // K3: MP hop 2 (wide)
  k_mp2<<<384, 512, 0, stream>>>(src_n, dst_n, ew_n, src_e, dst_e, ew_e, out);
  // K4: pool (scores/rank/CSR + 8-wave DCAP=12 power) + zero riders (skip acc)
  k_pool<<<16 + 2048, 512, 0, stream>>>(edge_u, edge_v, b_n, b_e, ws, out);
  // K5: dense xn/xe + sparse L0/L1 scatter (g=0 zeroes acc region first)
  k_out<<<6672, 256, 0, stream>>>(x_n, x_e, edge_u, edge_v, ws, out);
}